// Round 6
// baseline (871.787 us; speedup 1.0000x reference)
//
#include <hip/hip_runtime.h>
#include <hip/hip_bf16.h>
#include <math.h>

// Transformer block on gfx950. bf16 MFMA GEMMs (16x16x32), fp32 accumulate.
// Round-10: BK=32 double-buffered one-barrier K-loop (T3 minimum 2-phase).
// Same 32 KiB LDS as the single-buffered BK=64 body -> 4 blocks/CU preserved
// (round-3's BK=64 dbuf needed 64 KiB -> 2 blocks/CU -> regressed). stage(t+1)
// is issued BEFORE compute(t), so the barrier's implicit vmcnt(0) drain is
// covered by 16 MFMA + 8 ds_read per wave (x4 waves/SIMD) instead of exposed.
// Barrier count unchanged (24/loop). Chunk rotation re-derived for 64 B rows:
// slot=(chunk+row/2)&3 -> 2-way bank aliasing (free, m136). Math sequence is
// bit-identical to round-9 (same k-slice order) -> absmax must stay 0.03125.
// Algebra unchanged from round-9: q/k eliminated via Mt=Wk Wq^T (row-consts
// cancel in softmax; exact b_t via MODE 6), v folded into cproj via Wvc.

#define BM 128
#define BN 128
#define BK 32

typedef __attribute__((ext_vector_type(8))) short bf16x8;
typedef __attribute__((ext_vector_type(4))) float floatx4;

__device__ __forceinline__ short f2b(float f) {
  __hip_bfloat16 h = __float2bfloat16(f);
  return *reinterpret_cast<short*>(&h);
}
__device__ __forceinline__ float b2f(short s) {
  unsigned u = ((unsigned)(unsigned short)s) << 16;
  return __uint_as_float(u);
}

#if defined(__has_builtin)
#if __has_builtin(__builtin_amdgcn_global_load_lds)
#define HAS_GLLD 1
#endif
#endif

#ifdef HAS_GLLD
__device__ __forceinline__ void lds_dma16(const short* g, short* l) {
  __builtin_amdgcn_global_load_lds(
      (const __attribute__((address_space(1))) void*)g,
      (__attribute__((address_space(3))) void*)l, 16, 0, 0);
}
#endif

struct GP {
  const short* A; const short* B;
  long a_bs, b_bs;
  int lda, ldb;
  int a_kh; long a_hs;          // if a_kh>0: A addr = (k/a_kh)*a_hs + row*lda + k%a_kh
  const float* bias0;
  short* C0;
  float* Cf;
  int ldc, zmod, b_zmod;        // b_zmod>0: B base uses (z % b_zmod)
  long cz0, cz1, c_zs;
  int K, kchunk;                // kchunk>0: this z handles K range [z*kchunk, +kchunk)
  float alpha;
  int zoff;
};

// MODE 0: C0 = bf16(acc*alpha)            (CAUSAL=1 tile-skip; CAUSAL=2 K-limit)
// MODE 3: C0 = bf16(gelu(acc + bias0[col]))   [tanh-form gelu]
// MODE 4: Cf[z*c_zs + ...] = acc          (split-K fp32 partial)
// MODE 6: C0 = bf16((acc + bvec[(zoff+z/4)*4096 + (z&3)*1024 + col]) * alpha)
template<int MODE, int CAUSAL>
__device__ __forceinline__ void gemm_body(const GP& p)
{
  int bx = blockIdx.x;
  if (CAUSAL == 2) bx = gridDim.x - 1 - bx;   // longest K first
  const int m0 = bx * BM, n0 = blockIdx.y * BN;
  if (CAUSAL == 1 && n0 > m0 + (BM - 1)) return;
  const int z = blockIdx.z;
  const short* Ab = p.A + (size_t)z * p.a_bs;
  const short* Bb = p.B + (size_t)(p.b_zmod ? (z % p.b_zmod) : z) * p.b_bs;
  int kbeg = 0, kend = p.K;
  if (p.kchunk) { kbeg = z * p.kchunk; kend = kbeg + p.kchunk; }
  if (CAUSAL == 2) { int lim = m0 + BM; if (lim < kend) kend = lim; }

  // Row = 64 B (4 chunks of 16 B); chunk c of row r stored at slot (c + r/2) & 3.
  // Within a 16-lane quarter (fixed quad): row parity gives +0/+16 banks, row/2
  // rotation gives +0/4/8/12 -> 8 distinct 4-bank slots over 16 lanes = 2-way
  // aliasing only (free, m136). Double-buffered: 2 x (8+8) KiB = 32 KiB total.
  __shared__ __align__(16) short As[2][BM * BK];
  __shared__ __align__(16) short Bs[2][BN * BK];

  const int tid = threadIdx.x;
  const int lane = tid & 63, wave = tid >> 6;
  const int wm = (wave >> 1) * 64, wn = (wave & 1) * 64;
  const int l15 = lane & 15, quad = lane >> 4;
  const int rl = lane >> 2, pl = lane & 3;    // 16 rows x 4 chunk-slots per window

  floatx4 acc[4][4];
#pragma unroll
  for (int i = 0; i < 4; i++)
#pragma unroll
    for (int j = 0; j < 4; j++) acc[i][j] = (floatx4){0.f, 0.f, 0.f, 0.f};

  const int cs = (pl - (rl >> 1)) & 3;        // global chunk landing at LDS slot pl

  auto stage = [&](int k0, int d) {
    const short* Ak = Ab; int kb = k0;
    if (p.a_kh) { int h = k0 / p.a_kh; Ak = Ab + (size_t)h * p.a_hs; kb = k0 - h * p.a_kh; }
#pragma unroll
    for (int s = 0; s < 2; s++) {
      const int win = wave * 2 + s;           // 8 windows of 16 rows (1 KB each)
      const int row = win * 16 + rl;
      const short* ga = Ak + (size_t)(m0 + row) * p.lda + kb + cs * 8;
      const short* gb = Bb + (size_t)(n0 + row) * p.ldb + k0 + cs * 8;
#ifdef HAS_GLLD
      lds_dma16(ga, &As[d][win * 512]);
      lds_dma16(gb, &Bs[d][win * 512]);
#else
      *(int4*)&As[d][win * 512 + lane * 8] = *(const int4*)ga;
      *(int4*)&Bs[d][win * 512 + lane * 8] = *(const int4*)gb;
#endif
    }
  };

  // prologue: tile 0 into buf 0; barrier (drains it — once, not per-iter).
  stage(kbeg, 0);
  __syncthreads();

  int cur = 0;
  for (int k0 = kbeg; k0 < kend; k0 += BK) {
    // Issue next tile's DMA FIRST: the end-of-iter barrier's implicit
    // vmcnt(0) then lands after this iter's 16 MFMA + 8 ds_read (x4 waves/
    // SIMD) — latency covered instead of exposed. Disjoint buffers -> safe;
    // the same barrier orders the buf[cur] reads before next iter's overwrite.
    if (k0 + BK < kend) stage(k0 + BK, cur ^ 1);
    {
      bf16x8 fa[4], fb[4];
#pragma unroll
      for (int i = 0; i < 4; i++) {
        const int ra = wm + i * 16 + l15;
        fa[i] = *(const bf16x8*)&As[cur][ra * 32 + (((quad + (ra >> 1)) & 3) << 3)];
        const int rb = wn + i * 16 + l15;
        fb[i] = *(const bf16x8*)&Bs[cur][rb * 32 + (((quad + (rb >> 1)) & 3) << 3)];
      }
#pragma unroll
      for (int i = 0; i < 4; i++)
#pragma unroll
        for (int j = 0; j < 4; j++)
          acc[i][j] = __builtin_amdgcn_mfma_f32_16x16x32_bf16(fa[i], fb[j], acc[i][j], 0, 0, 0);
    }
    __syncthreads();
    cur ^= 1;
  }

  // C/D layout (m89): col = lane&15, row = quad*4 + reg
  const long coff = (long)(z % p.zmod) * p.cz0 + (long)(z / p.zmod) * p.cz1;
#pragma unroll
  for (int j = 0; j < 4; j++) {
    const int col = n0 + wn + j * 16 + l15;
    if constexpr (MODE == 0) {
#pragma unroll
      for (int i = 0; i < 4; i++) {
        const int rb = m0 + wm + i * 16 + quad * 4;
#pragma unroll
        for (int r = 0; r < 4; r++)
          p.C0[coff + (size_t)(rb + r) * p.ldc + col] = f2b(acc[i][j][r] * p.alpha);
      }
    } else if constexpr (MODE == 6) {
      const float* bb = p.bias0 + ((size_t)(p.zoff + (z >> 2)) * 4096 + (size_t)(z & 3) * 1024);
      const float bt = bb[col];
#pragma unroll
      for (int i = 0; i < 4; i++) {
        const int rb = m0 + wm + i * 16 + quad * 4;
#pragma unroll
        for (int r = 0; r < 4; r++)
          p.C0[coff + (size_t)(rb + r) * p.ldc + col] = f2b((acc[i][j][r] + bt) * p.alpha);
      }
    } else if constexpr (MODE == 4) {
#pragma unroll
      for (int i = 0; i < 4; i++) {
        const int rb = m0 + wm + i * 16 + quad * 4;
#pragma unroll
        for (int r = 0; r < 4; r++)
          p.Cf[(size_t)z * p.c_zs + (size_t)(rb + r) * p.ldc + col] = acc[i][j][r];
      }
    } else {  // MODE 3: gelu, tanh form: t*sigmoid(1.59577*t*(1+0.044715*t^2))
      const float bvv = p.bias0[col];
#pragma unroll
      for (int i = 0; i < 4; i++) {
        const int rb = m0 + wm + i * 16 + quad * 4;
#pragma unroll
        for (int r = 0; r < 4; r++) {
          float t = acc[i][j][r] + bvv;
          float u = 1.59576912160573071176f * t * (1.0f + 0.044715f * t * t);
          float gl = __fdividef(t, 1.0f + __expf(-u));
          p.C0[(size_t)(rb + r) * p.ldc + col] = f2b(gl);
        }
      }
    }
  }
}

// launch_bounds(256,4): 4 waves/EU -> <=128 VGPR+AGPR -> 4 blocks/CU (round-8 win)
__global__ void __launch_bounds__(256, 4) gemm_pre(GP p)   { gemm_body<0, 0>(p); }
__global__ void __launch_bounds__(256, 4) gemm_tmp(GP p)   { gemm_body<0, 0>(p); }
__global__ void __launch_bounds__(256, 4) gemm_sco(GP p)   { gemm_body<6, 1>(p); }
__global__ void __launch_bounds__(256, 4) gemm_pv(GP p)    { gemm_body<0, 2>(p); }
__global__ void __launch_bounds__(256, 4) gemm_cproj(GP p) { gemm_body<4, 0>(p); }
__global__ void __launch_bounds__(256, 4) gemm_fc(GP p)    { gemm_body<3, 0>(p); }
__global__ void __launch_bounds__(256, 4) gemm_mproj(GP p) { gemm_body<4, 0>(p); }

__global__ void __launch_bounds__(256) ln_kernel(
    const float* __restrict__ in, const float* __restrict__ g, const float* __restrict__ b,
    float* __restrict__ outf, short* __restrict__ outb)
{
  const long r = blockIdx.x;
  const float* x = in + r * 768;
  const int tid = threadIdx.x;
  float v0 = x[tid], v1 = x[tid + 256], v2 = x[tid + 512];
  float s = v0 + v1 + v2;
  float sq = v0 * v0 + v1 * v1 + v2 * v2;
  __shared__ float red[8];
  int lane = tid & 63, wave = tid >> 6;
#pragma unroll
  for (int o = 1; o < 64; o <<= 1) { s += __shfl_xor(s, o); sq += __shfl_xor(sq, o); }
  if (lane == 0) { red[wave] = s; red[4 + wave] = sq; }
  __syncthreads();
  s = red[0] + red[1] + red[2] + red[3];
  sq = red[4] + red[5] + red[6] + red[7];
  float mean = s * (1.0f / 768.0f);
  float var = sq * (1.0f / 768.0f) - mean * mean;
  float inv = rsqrtf(var + 1e-5f);
#pragma unroll
  for (int u = 0; u < 3; u++) {
    int c = tid + u * 256;
    float v = (u == 0) ? v0 : ((u == 1) ? v1 : v2);
    float y = (v - mean) * inv * g[c] + b[c];
    outf[r * 768 + c] = y;
    outb[r * 768 + c] = f2b(y);
  }
}

// y = sum(partials) + bias + resid; then LayerNorm(y)*g+b -> outf (fp32) + outb (bf16).
__global__ void __launch_bounds__(256) reduce_ln_kernel(
    const float* __restrict__ part, long pzs, int nsplit,
    const float* __restrict__ bias, const float* __restrict__ resid,
    const float* __restrict__ g, const float* __restrict__ b,
    float* __restrict__ outf, short* __restrict__ outb)
{
  const long r = blockIdx.x;
  const int tid = threadIdx.x;
  float y[3];
#pragma unroll
  for (int u = 0; u < 3; u++) {
    const int c = tid + u * 256;
    const size_t idx = (size_t)r * 768 + c;
    float s = part[idx];
    for (int zz = 1; zz < nsplit; zz++) s += part[(size_t)zz * pzs + idx];
    y[u] = s + bias[c] + resid[idx];
  }
  float s = y[0] + y[1] + y[2];
  float sq = y[0] * y[0] + y[1] * y[1] + y[2] * y[2];
  __shared__ float red[8];
  int lane = tid & 63, wave = tid >> 6;
#pragma unroll
  for (int o = 1; o < 64; o <<= 1) { s += __shfl_xor(s, o); sq += __shfl_xor(sq, o); }
  if (lane == 0) { red[wave] = s; red[4 + wave] = sq; }
  __syncthreads();
  s = red[0] + red[1] + red[2] + red[3];
  sq = red[4] + red[5] + red[6] + red[7];
  float mean = s * (1.0f / 768.0f);
  float var = sq * (1.0f / 768.0f) - mean * mean;
  float inv = rsqrtf(var + 1e-5f);
#pragma unroll
  for (int u = 0; u < 3; u++) {
    const int c = tid + u * 256;
    const float v = (y[u] - mean) * inv * g[c] + b[c];
    outf[(size_t)r * 768 + c] = v;
    outb[(size_t)r * 768 + c] = f2b(v);
  }
}

__global__ void __launch_bounds__(256) softmax_kernel(short* __restrict__ sc)
{
  const long gr = blockIdx.x;
  const int i = (int)(gr & 1023);
  short* row = sc + (gr >> 10) * (1024L * 1024) + (long)i * 1024;
  const int L = i + 1;
  const int tid = threadIdx.x;
  const int lane = tid & 63, wave = tid >> 6;
  __shared__ float red[4];
  float v[4];
  float mx = -3.0e38f;
#pragma unroll
  for (int s = 0; s < 4; s++) {
    int j = tid + s * 256;
    v[s] = (j < L) ? b2f(row[j]) : -3.0e38f;
    mx = fmaxf(mx, v[s]);
  }
#pragma unroll
  for (int o = 1; o < 64; o <<= 1) mx = fmaxf(mx, __shfl_xor(mx, o));
  if (lane == 0) red[wave] = mx;
  __syncthreads();
  mx = fmaxf(fmaxf(red[0], red[1]), fmaxf(red[2], red[3]));
  __syncthreads();
  float sum = 0.0f;
#pragma unroll
  for (int s = 0; s < 4; s++) {
    int j = tid + s * 256;
    if (j < L) { v[s] = __expf(v[s] - mx); sum += v[s]; }
  }
#pragma unroll
  for (int o = 1; o < 64; o <<= 1) sum += __shfl_xor(sum, o);
  if (lane == 0) red[wave] = sum;
  __syncthreads();
  sum = red[0] + red[1] + red[2] + red[3];
  float inv = 1.0f / sum;
#pragma unroll
  for (int s = 0; s < 4; s++) {
    int j = tid + s * 256;
    if (j < L) row[j] = f2b(v[s] * inv);
  }
  const int hi = i | 127;
  for (int j = L + tid; j <= hi; j += 256) row[j] = 0;
}

__global__ void __launch_bounds__(256) reduce_kernel(
    const float* __restrict__ part, long pzs, int nsplit,
    const float* __restrict__ bias, const float* __restrict__ resid,
    float* __restrict__ out)
{
  const size_t idx = ((size_t)blockIdx.x * 256 + threadIdx.x) * 4;
  float4 s = *(const float4*)&part[idx];
  for (int zz = 1; zz < nsplit; zz++) {
    float4 q = *(const float4*)&part[(size_t)zz * pzs + idx];
    s.x += q.x; s.y += q.y; s.z += q.z; s.w += q.w;
  }
  const int c = (int)(idx % 768);
  float4 b = *(const float4*)&bias[c];
  float4 r = *(const float4*)&resid[idx];
  *(float4*)&out[idx] = make_float4(s.x + b.x + r.x, s.y + b.y + r.y,
                                    s.z + b.z + r.z, s.w + b.w + r.w);
}

// W[R][C] fp32 -> Wt[C][R] bf16, per-z src/dst strides
__global__ void __launch_bounds__(256) transpose_kernel(
    const float* __restrict__ W, short* __restrict__ Wt, int R, int C, long szs, long dzs)
{
  __shared__ float tile[32][33];
  const int c0 = blockIdx.x * 32, r0 = blockIdx.y * 32;
  const float* Wz = W + (size_t)blockIdx.z * szs;
  short* Wtz = Wt + (size_t)blockIdx.z * dzs;
  const int tx = threadIdx.x, ty = threadIdx.y;
#pragma unroll
  for (int i = 0; i < 32; i += 8)
    tile[ty + i][tx] = Wz[(size_t)(r0 + ty + i) * C + (c0 + tx)];
  __syncthreads();
#pragma unroll
  for (int i = 0; i < 32; i += 8)
    Wtz[(size_t)(c0 + ty + i) * R + (r0 + tx)] = f2b(tile[tx][ty + i]);
}

// flat fp32 -> bf16 cast (for Wq/Wk/Wv row-major operands)
__global__ void __launch_bounds__(256) cast_kernel(
    const float* __restrict__ in, short* __restrict__ out, long n)
{
  const long i = ((long)blockIdx.x * 256 + threadIdx.x) * 4;
  if (i < n) {
    float4 v = *(const float4*)&in[i];
    short4 o;
    o.x = f2b(v.x); o.y = f2b(v.y); o.z = f2b(v.z); o.w = f2b(v.w);
    *(short4*)&out[i] = o;
  }
}

// vw[h][e] = sum_f Wk[h][e][f] * bq[h][f]   (one wave per (h,e))
__global__ void __launch_bounds__(256) vw_kernel(
    const float* __restrict__ Wk, const float* __restrict__ bq, float* __restrict__ vw)
{
  const int gid = blockIdx.x * 4 + (threadIdx.x >> 6);   // h*768+e, < 9216
  const int lane = threadIdx.x & 63;
  const int h = gid / 768;
  const float* row = Wk + (size_t)gid * 768;
  const float* bqh = bq + h * 768;
  float s = 0.f;
  for (int f = lane; f < 768; f += 64) s += row[f] * bqh[f];
#pragma unroll
  for (int o = 1; o < 64; o <<= 1) s += __shfl_xor(s, o);
  if (lane == 0) vw[gid] = s;
}

// bvec[h*4096 + r] = dot(x_f[r], vw[h])  (block per row r)
__global__ void __launch_bounds__(256) bvec_kernel(
    const float* __restrict__ x, const float* __restrict__ vw, float* __restrict__ bvec)
{
  const long r = blockIdx.x;
  const float* xr = x + r * 768;
  const int tid = threadIdx.x;
  const float v0 = xr[tid], v1 = xr[tid + 256], v2 = xr[tid + 512];
  __shared__ float red[4];
  const int lane = tid & 63, wave = tid >> 6;
  for (int h = 0; h < 12; h++) {
    const float* w = vw + h * 768;
    float s = v0 * w[tid] + v1 * w[tid + 256] + v2 * w[tid + 512];
#pragma unroll
    for (int o = 1; o < 64; o <<= 1) s += __shfl_xor(s, o);
    if (lane == 0) red[wave] = s;
    __syncthreads();
    if (tid == 0) bvec[(size_t)h * 4096 + r] = red[0] + red[1] + red[2] + red[3];
    __syncthreads();
  }
}

__global__ void __launch_bounds__(256) bcv_init(const float* __restrict__ bc, float* __restrict__ bcv)
{
  const int j = blockIdx.x * 256 + threadIdx.x;
  if (j < 768) bcv[j] = bc[j];
}

// bcv[j] += sum_i bv_flat[i] * Wc[i][j]  over 256-row chunks (grid.y)
__global__ void __launch_bounds__(256) bcv_acc(
    const float* __restrict__ Wc, const float* __restrict__ bv, float* __restrict__ bcv)
{
  const int j = blockIdx.x * 256 + threadIdx.x;
  const int i0 = blockIdx.y * 256;
  float s = 0.f;
  for (int i = i0; i < i0 + 256; i++) s += bv[i] * Wc[(size_t)i * 768 + j];
  atomicAdd(&bcv[j], s);
}

extern "C" void kernel_launch(void* const* d_in, const int* in_sizes, int n_in,
                              void* d_out, int out_size, void* d_ws, size_t ws_size,
                              hipStream_t stream)
{
  (void)in_sizes; (void)n_in; (void)out_size;
  const float* inputs = (const float*)d_in[0];
  const float* g1  = (const float*)d_in[1];
  const float* b1  = (const float*)d_in[2];
  const float* Wq  = (const float*)d_in[3];
  const float* bq  = (const float*)d_in[4];
  const float* Wk  = (const float*)d_in[5];
  const float* bk  = (const float*)d_in[6];  (void)bk;   // cancels in softmax
  const float* Wv  = (const float*)d_in[7];
  const float* bv  = (const float*)d_in[8];
  const float* Wc  = (const float*)d_in[9];
  const float* bc  = (const float*)d_in[10];
  const float* g2  = (const float*)d_in[11];
  const float* b2  = (const float*)d_in[12];
  const float* Wfc = (const float*)d_in[13];
  const float* bfc = (const float*)d_in[14];
  const float* Wp  = (const float*)d_in[15];
  const float* bp  = (const float*)d_in[16];
  float* out = (float*)d_out;

  const size_t NS = 4096, E = 768, S = 1024;

  char* base = (char*)d_ws;
  size_t off = 0;
  auto alloc = [&](size_t n) { char* r = base + off; off = (off + n + 255) & ~(size_t)255; return r; };

  // ---- persistent region ----
  float* x_f  = (float*)alloc(NS * E * 4);
  short* x_b  = (short*)alloc(NS * E * 2);
  short* xT   = (short*)alloc(NS * E * 2);           // [n][768][1024]
  short* Mt   = (short*)alloc(12 * E * E * 2);       // Mt_h[e'][e] = (Wk Wq^T)
  short* WvcT = (short*)alloc(E * 9216 * 2);         // [j][h*768+e] = (Wv_h Wc_h)^T
  short* WcT  = (short*)alloc(E * 9216 * 2);         // Wc^T (feeds WvcT gemm)
  short* WfcT = (short*)alloc(3072 * E * 2);
  short* WpT  = (short*)alloc(E * 3072 * 2);
  float* vw   = (float*)alloc(12 * E * 4);           // Wk_h @ bq_h
  float* bvec = (float*)alloc(12 * NS * 4);          // x . vw  [h][n*1024+t]
  float* bcv  = (float*)alloc(E * 4);                // bc + sum_h bv_h Wc_h
  short* cat  = (short*)alloc(12 * NS * E * 2);      // attnx, head-major; aliases partB

  // ---- overlay region R ----
  char* Rp = base + off;
  const size_t R_size = (ws_size > off) ? (ws_size - off) : 0;

  // setup scratch (dead after precompute gemms)
  short* Wq_c = (short*)Rp;                          // 14.2 MB
  short* Wk_c = Wq_c + 12 * E * E;
  short* Wv_c = Wk_c + 12 * E * E;

  // attention pool: tmp per head + scores
  const size_t per_h = (NS * E * 2) + 4 * S * S * 2;
  static const int Gs[5] = {6, 4, 3, 2, 1};
  int G = 1;
  for (int i = 0; i < 5; i++)
    if ((size_t)Gs[i] * per_h <= R_size) { G = Gs[i]; break; }
  short* tmp_g = (short*)Rp;                         // [G][4096][768]
  short* sc_g  = tmp_g + (size_t)G * NS * E;         // [g*4+n][1024][1024]

  // post-attention overlay
  size_t o2 = 0;
  float* partA = (float*)(Rp + o2); o2 += 4 * NS * E * 4;
  float* y2_f  = (float*)(Rp + o2); o2 += NS * E * 4;
  short* y2_b  = (short*)(Rp + o2); o2 += NS * E * 2;
  short* h_b   = (short*)(Rp + o2); o2 += NS * 3072 * 2;
  float* partB = (float*)cat;

  const dim3 tb(32, 8);
  // weight preprocessing
  transpose_kernel<<<dim3(24, 288, 1), tb, 0, stream>>>(Wc, WcT, 9216, 768, 0, 0);
  transpose_kernel<<<dim3(96, 24, 1),  tb, 0, stream>>>(Wfc, WfcT, 768, 3072, 0, 0);
  transpose_kernel<<<dim3(24, 96, 1),  tb, 0, stream>>>(Wp, WpT, 3072, 768, 0, 0);
  const long WN = 12L * E * E;
  cast_kernel<<<(WN / 4 + 255) / 256, 256, 0, stream>>>(Wq, Wq_c, WN);
  cast_kernel<<<(WN / 4 + 255) / 256, 256, 0, stream>>>(Wk, Wk_c, WN);
  cast_kernel<<<(WN / 4 + 255) / 256, 256, 0, stream>>>(Wv, Wv_c, WN);
  {  // Mt_h = Wk_h @ Wq_h^T : C[e'][e] = sum_f Wk[e'][f] Wq[e][f]
    GP p{};
    p.A = Wk_c; p.lda = 768; p.a_bs = (long)(E * E);
    p.B = Wq_c; p.ldb = 768; p.b_bs = (long)(E * E);
    p.C0 = Mt; p.ldc = 768; p.zmod = 1; p.cz0 = 0; p.cz1 = (long)(E * E);
    p.K = 768; p.alpha = 1.0f;
    gemm_pre<<<dim3(6, 6, 12), 256, 0, stream>>>(p);
  }
  {  // WvcT[j][h*768+e] = sum_f WcT[j][h*768+f] * Wv[e][f]
    GP p{};
    p.A = WcT; p.lda = 9216; p.a_bs = 768;
    p.B = Wv_c; p.ldb = 768; p.b_bs = (long)(E * E);
    p.C0 = WvcT; p.ldc = 9216; p.zmod = 1; p.cz0 = 0; p.cz1 = 768;
    p.K = 768; p.alpha = 1.0f;
    gemm_pre<<<dim3(6, 6, 12), 256, 0, stream>>>(p);
  }
  vw_kernel<<<2304, 256, 0, stream>>>(Wk, bq, vw);
  bcv_init<<<3, 256, 0, stream>>>(bc, bcv);
  bcv_acc<<<dim3(3, 36), 256, 0, stream>>>(Wc, bv, bcv);

  ln_kernel<<<4096, 256, 0, stream>>>(inputs, g1, b1, x_f, x_b);
  transpose_kernel<<<dim3(24, 32, 4), tb, 0, stream>>>(x_f, xT, 1024, 768,
                                                       (long)(S * E), (long)(E * S));
  bvec_kernel<<<4096, 256, 0, stream>>>(x_f, vw, bvec);

  const float sca = 0.03608439182435161f;  // 1/sqrt(768)
  for (int h0 = 0; h0 < 12; h0 += G) {
    {  // tmp = x @ Mt_h  (replaces q AND k projections)
      GP p{};
      p.A = x_b; p.lda = 768; p.a_bs = 0;
      p.B = Mt + (size_t)h0 * E * E; p.ldb = 768; p.b_bs = (long)(E * E);
      p.C0 = tmp_g; p.ldc = 768; p.zmod = 1; p.cz0 = 0; p.cz1 = (long)(NS * E);
      p.K = 768; p.alpha = 1.0f;
      gemm_tmp<<<dim3(32, 6, G), 256, 0, stream>>>(p);
    }
    {  // scores = (tmp x^T + b_t) / sqrt(E); row-const terms cancel in softmax
      GP p{};
      p.A = tmp_g; p.lda = 768; p.a_bs = (long)(S * E);
      p.B = x_b; p.ldb = 768; p.b_bs = (long)(S * E); p.b_zmod = 4;
      p.bias0 = bvec; p.zoff = h0;
      p.C0 = sc_g; p.ldc = 1024; p.zmod = 1; p.cz0 = 0; p.cz1 = (long)(S * S);
      p.K = 768; p.alpha = sca;
      gemm_sco<<<dim3(8, 8, 4 * G), 256, 0, stream>>>(p);
    }
    softmax_kernel<<<4 * G * 1024, 256, 0, stream>>>(sc_g);
    {  // attnx = attn @ x -> cat[h][4096][768]   (v folded into cproj)
      GP p{};
      p.A = sc_g; p.lda = 1024; p.a_bs = (long)(S * S);
      p.B = xT; p.ldb = 1024; p.b_bs = (long)(E * S); p.b_zmod = 4;
      p.C0 = cat + (size_t)h0 * NS * E; p.ldc = 768;
      p.zmod = 4; p.cz0 = (long)(S * E); p.cz1 = (long)(NS * E);
      p.K = 1024; p.alpha = 1.0f;
      gemm_pv<<<dim3(8, 6, 4 * G), 256, 0, stream>>>(p);
    }
  }

  {  // c_proj (with folded Wv): split-K=4 over head-major attnx
    GP p{};
    p.A = cat; p.lda = 768; p.a_kh = 768; p.a_hs = (long)(NS * E);
    p.B = WvcT; p.ldb = 9216;
    p.Cf = partA; p.ldc = 768; p.c_zs = (long)(NS * E); p.zmod = 1;
    p.K = 9216; p.kchunk = 2304; p.alpha = 1.0f;
    gemm_cproj<<<dim3(32, 6, 4), 256, 0, stream>>>(p);
  }
  // y = sum(partA) + (bc + bvc) + x_f; y2 = LN(y)
  reduce_ln_kernel<<<4096, 256, 0, stream>>>(partA, (long)(NS * E), 4, bcv, x_f,
                                             g2, b2, y2_f, y2_b);

  {  // fc + tanh-form gelu
    GP p{};
    p.A = y2_b; p.lda = 768;
    p.B = WfcT; p.ldb = 768;
    p.bias0 = bfc; p.C0 = h_b; p.ldc = 3072; p.zmod = 1;
    p.K = 768; p.alpha = 1.0f;
    gemm_fc<<<dim3(32, 24, 1), 256, 0, stream>>>(p);
  }
  {  // proj split-K=4
    GP p{};
    p.A = h_b; p.lda = 3072;
    p.B = WpT; p.ldb = 3072;
    p.Cf = partB; p.ldc = 768; p.c_zs = (long)(NS * E); p.zmod = 1;
    p.K = 3072; p.kchunk = 768; p.alpha = 1.0f;
    gemm_mproj<<<dim3(32, 6, 4), 256, 0, stream>>>(p);
  }
  reduce_kernel<<<3072, 256, 0, stream>>>(partB, (long)(NS * E), 4, bp, y2_f, out);
}

// Round 7
// 775.802 us; speedup vs baseline: 1.1237x; 1.1237x over previous
//
#include <hip/hip_runtime.h>
#include <hip/hip_bf16.h>
#include <math.h>

// Transformer block on gfx950. bf16 MFMA GEMMs (16x16x32), fp32 accumulate.
// Round-11: consolidation. REVERT round-10's BK=32 dbuf (3rd failed pipelining
// attempt: 818->872us; m99-m141 pattern confirmed — the 2-barrier 128^2 body
// at 4 blocks/CU is its own plateau). Back to the verified round-9 body
// (817.9us) with two zero-risk deltas:
//  (a) G=6 -> G=4: every attention grid now fits the 1024 resident-block
//      capacity exactly (tmp 768, sco 1024, pv 768) — removes the 128-block
//      straggler tails measured with 1152/1536-block launches (~25us).
//  (b) bvec fused into ln_kernel (LN'd row already in registers) — removes a
//      launch and a 12.6MB re-read of x_f.
// Algebra unchanged from round-9: q/k eliminated via Mt=Wk Wq^T (row-consts
// cancel in softmax; exact b_t via MODE 6), v folded into cproj via Wvc.

#define BM 128
#define BN 128
#define BK 64

typedef __attribute__((ext_vector_type(8))) short bf16x8;
typedef __attribute__((ext_vector_type(4))) float floatx4;

__device__ __forceinline__ short f2b(float f) {
  __hip_bfloat16 h = __float2bfloat16(f);
  return *reinterpret_cast<short*>(&h);
}
__device__ __forceinline__ float b2f(short s) {
  unsigned u = ((unsigned)(unsigned short)s) << 16;
  return __uint_as_float(u);
}

#if defined(__has_builtin)
#if __has_builtin(__builtin_amdgcn_global_load_lds)
#define HAS_GLLD 1
#endif
#endif

#ifdef HAS_GLLD
__device__ __forceinline__ void lds_dma16(const short* g, short* l) {
  __builtin_amdgcn_global_load_lds(
      (const __attribute__((address_space(1))) void*)g,
      (__attribute__((address_space(3))) void*)l, 16, 0, 0);
}
#endif

struct GP {
  const short* A; const short* B;
  long a_bs, b_bs;
  int lda, ldb;
  int a_kh; long a_hs;          // if a_kh>0: A addr = (k/a_kh)*a_hs + row*lda + k%a_kh
  const float* bias0;
  short* C0;
  float* Cf;
  int ldc, zmod, b_zmod;        // b_zmod>0: B base uses (z % b_zmod)
  long cz0, cz1, c_zs;
  int K, kchunk;                // kchunk>0: this z handles K range [z*kchunk, +kchunk)
  float alpha;
  int zoff;
};

// MODE 0: C0 = bf16(acc*alpha)            (CAUSAL=1 tile-skip; CAUSAL=2 K-limit)
// MODE 3: C0 = bf16(gelu(acc + bias0[col]))   [tanh-form gelu]
// MODE 4: Cf[z*c_zs + ...] = acc          (split-K fp32 partial)
// MODE 6: C0 = bf16((acc + bvec[(zoff+z/4)*4096 + (z&3)*1024 + col]) * alpha)
template<int MODE, int CAUSAL>
__device__ __forceinline__ void gemm_body(const GP& p)
{
  int bx = blockIdx.x;
  if (CAUSAL == 2) bx = gridDim.x - 1 - bx;   // longest K first
  const int m0 = bx * BM, n0 = blockIdx.y * BN;
  if (CAUSAL == 1 && n0 > m0 + (BM - 1)) return;
  const int z = blockIdx.z;
  const short* Ab = p.A + (size_t)z * p.a_bs;
  const short* Bb = p.B + (size_t)(p.b_zmod ? (z % p.b_zmod) : z) * p.b_bs;
  int kbeg = 0, kend = p.K;
  if (p.kchunk) { kbeg = z * p.kchunk; kend = kbeg + p.kchunk; }
  if (CAUSAL == 2) { int lim = m0 + BM; if (lim < kend) kend = lim; }

  // Row = 128 B (8 chunks of 16 B); chunk c of row r stored at pos (c + r) & 7.
  // ds_read_b128: within a 16-lane quarter (fixed quad) rows cover each rotation
  // twice -> 2-way bank aliasing only (free, m136).
  __shared__ __align__(16) short As[BM * BK];
  __shared__ __align__(16) short Bs[BN * BK];

  const int tid = threadIdx.x;
  const int lane = tid & 63, wave = tid >> 6;
  const int wm = (wave >> 1) * 64, wn = (wave & 1) * 64;
  const int l15 = lane & 15, quad = lane >> 4;
  const int rl = lane >> 3, pl = lane & 7;    // 8 rows x 8 chunk-slots per window

  floatx4 acc[4][4];
#pragma unroll
  for (int i = 0; i < 4; i++)
#pragma unroll
    for (int j = 0; j < 4; j++) acc[i][j] = (floatx4){0.f, 0.f, 0.f, 0.f};

  const int cs = (pl - rl) & 7;               // global chunk landing at LDS pos pl

  for (int k0 = kbeg; k0 < kend; k0 += BK) {
    const short* Ak = Ab; int kb = k0;
    if (p.a_kh) { int h = k0 / p.a_kh; Ak = Ab + (size_t)h * p.a_hs; kb = k0 - h * p.a_kh; }
#pragma unroll
    for (int s = 0; s < 4; s++) {
      const int win = wave * 4 + s;           // 16 windows of 8 rows (1 KB each)
      const int row = win * 8 + rl;
      const short* ga = Ak + (size_t)(m0 + row) * p.lda + kb + cs * 8;
      const short* gb = Bb + (size_t)(n0 + row) * p.ldb + k0 + cs * 8;
#ifdef HAS_GLLD
      lds_dma16(ga, &As[win * 512]);
      lds_dma16(gb, &Bs[win * 512]);
#else
      *(int4*)&As[win * 512 + lane * 8] = *(const int4*)ga;
      *(int4*)&Bs[win * 512 + lane * 8] = *(const int4*)gb;
#endif
    }
    __syncthreads();
#pragma unroll
    for (int t = 0; t < 2; t++) {             // two 16x16x32 k-steps per BK=64 tile
      bf16x8 fa[4], fb[4];
#pragma unroll
      for (int i = 0; i < 4; i++) {
        const int ra = wm + i * 16 + l15;
        fa[i] = *(const bf16x8*)&As[ra * 64 + (((t << 2) + quad + ra) & 7) * 8];
        const int rb = wn + i * 16 + l15;
        fb[i] = *(const bf16x8*)&Bs[rb * 64 + (((t << 2) + quad + rb) & 7) * 8];
      }
#pragma unroll
      for (int i = 0; i < 4; i++)
#pragma unroll
        for (int j = 0; j < 4; j++)
          acc[i][j] = __builtin_amdgcn_mfma_f32_16x16x32_bf16(fa[i], fb[j], acc[i][j], 0, 0, 0);
    }
    __syncthreads();
  }

  // C/D layout (m89): col = lane&15, row = quad*4 + reg
  const long coff = (long)(z % p.zmod) * p.cz0 + (long)(z / p.zmod) * p.cz1;
#pragma unroll
  for (int j = 0; j < 4; j++) {
    const int col = n0 + wn + j * 16 + l15;
    if constexpr (MODE == 0) {
#pragma unroll
      for (int i = 0; i < 4; i++) {
        const int rb = m0 + wm + i * 16 + quad * 4;
#pragma unroll
        for (int r = 0; r < 4; r++)
          p.C0[coff + (size_t)(rb + r) * p.ldc + col] = f2b(acc[i][j][r] * p.alpha);
      }
    } else if constexpr (MODE == 6) {
      const float* bb = p.bias0 + ((size_t)(p.zoff + (z >> 2)) * 4096 + (size_t)(z & 3) * 1024);
      const float bt = bb[col];
#pragma unroll
      for (int i = 0; i < 4; i++) {
        const int rb = m0 + wm + i * 16 + quad * 4;
#pragma unroll
        for (int r = 0; r < 4; r++)
          p.C0[coff + (size_t)(rb + r) * p.ldc + col] = f2b((acc[i][j][r] + bt) * p.alpha);
      }
    } else if constexpr (MODE == 4) {
#pragma unroll
      for (int i = 0; i < 4; i++) {
        const int rb = m0 + wm + i * 16 + quad * 4;
#pragma unroll
        for (int r = 0; r < 4; r++)
          p.Cf[(size_t)z * p.c_zs + (size_t)(rb + r) * p.ldc + col] = acc[i][j][r];
      }
    } else {  // MODE 3: gelu, tanh form: t*sigmoid(1.59577*t*(1+0.044715*t^2))
      const float bvv = p.bias0[col];
#pragma unroll
      for (int i = 0; i < 4; i++) {
        const int rb = m0 + wm + i * 16 + quad * 4;
#pragma unroll
        for (int r = 0; r < 4; r++) {
          float t = acc[i][j][r] + bvv;
          float u = 1.59576912160573071176f * t * (1.0f + 0.044715f * t * t);
          float gl = __fdividef(t, 1.0f + __expf(-u));
          p.C0[(size_t)(rb + r) * p.ldc + col] = f2b(gl);
        }
      }
    }
  }
}

// launch_bounds(256,4): 4 waves/EU -> <=128 VGPR+AGPR -> 4 blocks/CU (round-8 win)
__global__ void __launch_bounds__(256, 4) gemm_pre(GP p)   { gemm_body<0, 0>(p); }
__global__ void __launch_bounds__(256, 4) gemm_tmp(GP p)   { gemm_body<0, 0>(p); }
__global__ void __launch_bounds__(256, 4) gemm_sco(GP p)   { gemm_body<6, 1>(p); }
__global__ void __launch_bounds__(256, 4) gemm_pv(GP p)    { gemm_body<0, 2>(p); }
__global__ void __launch_bounds__(256, 4) gemm_cproj(GP p) { gemm_body<4, 0>(p); }
__global__ void __launch_bounds__(256, 4) gemm_fc(GP p)    { gemm_body<3, 0>(p); }
__global__ void __launch_bounds__(256, 4) gemm_mproj(GP p) { gemm_body<4, 0>(p); }

// LayerNorm + fused bvec: bvec[h*4096+r] = dot(LN_row, vw[h]) for h=0..11.
// Same per-lane 3-term + 64-lane shfl tree + 4-wave sum order as the old
// bvec_kernel (bit-identical results).
__global__ void __launch_bounds__(256) ln_kernel(
    const float* __restrict__ in, const float* __restrict__ g, const float* __restrict__ b,
    const float* __restrict__ vw, float* __restrict__ bvec,
    float* __restrict__ outf, short* __restrict__ outb)
{
  const long r = blockIdx.x;
  const float* x = in + r * 768;
  const int tid = threadIdx.x;
  float v0 = x[tid], v1 = x[tid + 256], v2 = x[tid + 512];
  float s = v0 + v1 + v2;
  float sq = v0 * v0 + v1 * v1 + v2 * v2;
  __shared__ float red[8];
  int lane = tid & 63, wave = tid >> 6;
#pragma unroll
  for (int o = 1; o < 64; o <<= 1) { s += __shfl_xor(s, o); sq += __shfl_xor(sq, o); }
  if (lane == 0) { red[wave] = s; red[4 + wave] = sq; }
  __syncthreads();
  s = red[0] + red[1] + red[2] + red[3];
  sq = red[4] + red[5] + red[6] + red[7];
  float mean = s * (1.0f / 768.0f);
  float var = sq * (1.0f / 768.0f) - mean * mean;
  float inv = rsqrtf(var + 1e-5f);
  float yv[3];
#pragma unroll
  for (int u = 0; u < 3; u++) {
    int c = tid + u * 256;
    float v = (u == 0) ? v0 : ((u == 1) ? v1 : v2);
    float y = (v - mean) * inv * g[c] + b[c];
    yv[u] = y;
    outf[r * 768 + c] = y;
    outb[r * 768 + c] = f2b(y);
  }
  // fused bvec
  for (int h = 0; h < 12; h++) {
    const float* w = vw + h * 768;
    float t = yv[0] * w[tid] + yv[1] * w[tid + 256] + yv[2] * w[tid + 512];
#pragma unroll
    for (int o = 1; o < 64; o <<= 1) t += __shfl_xor(t, o);
    __syncthreads();
    if (lane == 0) red[wave] = t;
    __syncthreads();
    if (tid == 0) bvec[(size_t)h * 4096 + r] = red[0] + red[1] + red[2] + red[3];
  }
}

// y = sum(partials) + bias + resid; then LayerNorm(y)*g+b -> outf (fp32) + outb (bf16).
__global__ void __launch_bounds__(256) reduce_ln_kernel(
    const float* __restrict__ part, long pzs, int nsplit,
    const float* __restrict__ bias, const float* __restrict__ resid,
    const float* __restrict__ g, const float* __restrict__ b,
    float* __restrict__ outf, short* __restrict__ outb)
{
  const long r = blockIdx.x;
  const int tid = threadIdx.x;
  float y[3];
#pragma unroll
  for (int u = 0; u < 3; u++) {
    const int c = tid + u * 256;
    const size_t idx = (size_t)r * 768 + c;
    float s = part[idx];
    for (int zz = 1; zz < nsplit; zz++) s += part[(size_t)zz * pzs + idx];
    y[u] = s + bias[c] + resid[idx];
  }
  float s = y[0] + y[1] + y[2];
  float sq = y[0] * y[0] + y[1] * y[1] + y[2] * y[2];
  __shared__ float red[8];
  int lane = tid & 63, wave = tid >> 6;
#pragma unroll
  for (int o = 1; o < 64; o <<= 1) { s += __shfl_xor(s, o); sq += __shfl_xor(sq, o); }
  if (lane == 0) { red[wave] = s; red[4 + wave] = sq; }
  __syncthreads();
  s = red[0] + red[1] + red[2] + red[3];
  sq = red[4] + red[5] + red[6] + red[7];
  float mean = s * (1.0f / 768.0f);
  float var = sq * (1.0f / 768.0f) - mean * mean;
  float inv = rsqrtf(var + 1e-5f);
#pragma unroll
  for (int u = 0; u < 3; u++) {
    const int c = tid + u * 256;
    const float v = (y[u] - mean) * inv * g[c] + b[c];
    outf[(size_t)r * 768 + c] = v;
    outb[(size_t)r * 768 + c] = f2b(v);
  }
}

__global__ void __launch_bounds__(256) softmax_kernel(short* __restrict__ sc)
{
  const long gr = blockIdx.x;
  const int i = (int)(gr & 1023);
  short* row = sc + (gr >> 10) * (1024L * 1024) + (long)i * 1024;
  const int L = i + 1;
  const int tid = threadIdx.x;
  const int lane = tid & 63, wave = tid >> 6;
  __shared__ float red[4];
  float v[4];
  float mx = -3.0e38f;
#pragma unroll
  for (int s = 0; s < 4; s++) {
    int j = tid + s * 256;
    v[s] = (j < L) ? b2f(row[j]) : -3.0e38f;
    mx = fmaxf(mx, v[s]);
  }
#pragma unroll
  for (int o = 1; o < 64; o <<= 1) mx = fmaxf(mx, __shfl_xor(mx, o));
  if (lane == 0) red[wave] = mx;
  __syncthreads();
  mx = fmaxf(fmaxf(red[0], red[1]), fmaxf(red[2], red[3]));
  __syncthreads();
  float sum = 0.0f;
#pragma unroll
  for (int s = 0; s < 4; s++) {
    int j = tid + s * 256;
    if (j < L) { v[s] = __expf(v[s] - mx); sum += v[s]; }
  }
#pragma unroll
  for (int o = 1; o < 64; o <<= 1) sum += __shfl_xor(sum, o);
  if (lane == 0) red[wave] = sum;
  __syncthreads();
  sum = red[0] + red[1] + red[2] + red[3];
  float inv = 1.0f / sum;
#pragma unroll
  for (int s = 0; s < 4; s++) {
    int j = tid + s * 256;
    if (j < L) row[j] = f2b(v[s] * inv);
  }
  const int hi = i | 127;
  for (int j = L + tid; j <= hi; j += 256) row[j] = 0;
}

__global__ void __launch_bounds__(256) reduce_kernel(
    const float* __restrict__ part, long pzs, int nsplit,
    const float* __restrict__ bias, const float* __restrict__ resid,
    float* __restrict__ out)
{
  const size_t idx = ((size_t)blockIdx.x * 256 + threadIdx.x) * 4;
  float4 s = *(const float4*)&part[idx];
  for (int zz = 1; zz < nsplit; zz++) {
    float4 q = *(const float4*)&part[(size_t)zz * pzs + idx];
    s.x += q.x; s.y += q.y; s.z += q.z; s.w += q.w;
  }
  const int c = (int)(idx % 768);
  float4 b = *(const float4*)&bias[c];
  float4 r = *(const float4*)&resid[idx];
  *(float4*)&out[idx] = make_float4(s.x + b.x + r.x, s.y + b.y + r.y,
                                    s.z + b.z + r.z, s.w + b.w + r.w);
}

// W[R][C] fp32 -> Wt[C][R] bf16, per-z src/dst strides
__global__ void __launch_bounds__(256) transpose_kernel(
    const float* __restrict__ W, short* __restrict__ Wt, int R, int C, long szs, long dzs)
{
  __shared__ float tile[32][33];
  const int c0 = blockIdx.x * 32, r0 = blockIdx.y * 32;
  const float* Wz = W + (size_t)blockIdx.z * szs;
  short* Wtz = Wt + (size_t)blockIdx.z * dzs;
  const int tx = threadIdx.x, ty = threadIdx.y;
#pragma unroll
  for (int i = 0; i < 32; i += 8)
    tile[ty + i][tx] = Wz[(size_t)(r0 + ty + i) * C + (c0 + tx)];
  __syncthreads();
#pragma unroll
  for (int i = 0; i < 32; i += 8)
    Wtz[(size_t)(c0 + ty + i) * R + (r0 + tx)] = f2b(tile[tx][ty + i]);
}

// flat fp32 -> bf16 cast (for Wq/Wk/Wv row-major operands)
__global__ void __launch_bounds__(256) cast_kernel(
    const float* __restrict__ in, short* __restrict__ out, long n)
{
  const long i = ((long)blockIdx.x * 256 + threadIdx.x) * 4;
  if (i < n) {
    float4 v = *(const float4*)&in[i];
    short4 o;
    o.x = f2b(v.x); o.y = f2b(v.y); o.z = f2b(v.z); o.w = f2b(v.w);
    *(short4*)&out[i] = o;
  }
}

// vw[h][e] = sum_f Wk[h][e][f] * bq[h][f]   (one wave per (h,e))
__global__ void __launch_bounds__(256) vw_kernel(
    const float* __restrict__ Wk, const float* __restrict__ bq, float* __restrict__ vw)
{
  const int gid = blockIdx.x * 4 + (threadIdx.x >> 6);   // h*768+e, < 9216
  const int lane = threadIdx.x & 63;
  const int h = gid / 768;
  const float* row = Wk + (size_t)gid * 768;
  const float* bqh = bq + h * 768;
  float s = 0.f;
  for (int f = lane; f < 768; f += 64) s += row[f] * bqh[f];
#pragma unroll
  for (int o = 1; o < 64; o <<= 1) s += __shfl_xor(s, o);
  if (lane == 0) vw[gid] = s;
}

__global__ void __launch_bounds__(256) bcv_init(const float* __restrict__ bc, float* __restrict__ bcv)
{
  const int j = blockIdx.x * 256 + threadIdx.x;
  if (j < 768) bcv[j] = bc[j];
}

// bcv[j] += sum_i bv_flat[i] * Wc[i][j]  over 256-row chunks (grid.y)
__global__ void __launch_bounds__(256) bcv_acc(
    const float* __restrict__ Wc, const float* __restrict__ bv, float* __restrict__ bcv)
{
  const int j = blockIdx.x * 256 + threadIdx.x;
  const int i0 = blockIdx.y * 256;
  float s = 0.f;
  for (int i = i0; i < i0 + 256; i++) s += bv[i] * Wc[(size_t)i * 768 + j];
  atomicAdd(&bcv[j], s);
}

extern "C" void kernel_launch(void* const* d_in, const int* in_sizes, int n_in,
                              void* d_out, int out_size, void* d_ws, size_t ws_size,
                              hipStream_t stream)
{
  (void)in_sizes; (void)n_in; (void)out_size;
  const float* inputs = (const float*)d_in[0];
  const float* g1  = (const float*)d_in[1];
  const float* b1  = (const float*)d_in[2];
  const float* Wq  = (const float*)d_in[3];
  const float* bq  = (const float*)d_in[4];
  const float* Wk  = (const float*)d_in[5];
  const float* bk  = (const float*)d_in[6];  (void)bk;   // cancels in softmax
  const float* Wv  = (const float*)d_in[7];
  const float* bv  = (const float*)d_in[8];
  const float* Wc  = (const float*)d_in[9];
  const float* bc  = (const float*)d_in[10];
  const float* g2  = (const float*)d_in[11];
  const float* b2  = (const float*)d_in[12];
  const float* Wfc = (const float*)d_in[13];
  const float* bfc = (const float*)d_in[14];
  const float* Wp  = (const float*)d_in[15];
  const float* bp  = (const float*)d_in[16];
  float* out = (float*)d_out;

  const size_t NS = 4096, E = 768, S = 1024;

  char* base = (char*)d_ws;
  size_t off = 0;
  auto alloc = [&](size_t n) { char* r = base + off; off = (off + n + 255) & ~(size_t)255; return r; };

  // ---- persistent region ----
  float* x_f  = (float*)alloc(NS * E * 4);
  short* x_b  = (short*)alloc(NS * E * 2);
  short* xT   = (short*)alloc(NS * E * 2);           // [n][768][1024]
  short* Mt   = (short*)alloc(12 * E * E * 2);       // Mt_h[e'][e] = (Wk Wq^T)
  short* WvcT = (short*)alloc(E * 9216 * 2);         // [j][h*768+e] = (Wv_h Wc_h)^T
  short* WcT  = (short*)alloc(E * 9216 * 2);         // Wc^T (feeds WvcT gemm)
  short* WfcT = (short*)alloc(3072 * E * 2);
  short* WpT  = (short*)alloc(E * 3072 * 2);
  float* vw   = (float*)alloc(12 * E * 4);           // Wk_h @ bq_h
  float* bvec = (float*)alloc(12 * NS * 4);          // x . vw  [h][n*1024+t]
  float* bcv  = (float*)alloc(E * 4);                // bc + sum_h bv_h Wc_h
  short* cat  = (short*)alloc(12 * NS * E * 2);      // attnx, head-major; aliases partB

  // ---- overlay region R ----
  char* Rp = base + off;
  const size_t R_size = (ws_size > off) ? (ws_size - off) : 0;

  // setup scratch (dead after precompute gemms)
  short* Wq_c = (short*)Rp;                          // 14.2 MB
  short* Wk_c = Wq_c + 12 * E * E;
  short* Wv_c = Wk_c + 12 * E * E;

  // attention pool: tmp per head + scores. G=4 keeps every grid <= 1024
  // resident blocks (4/CU x 256) — no straggler tails.
  const size_t per_h = (NS * E * 2) + 4 * S * S * 2;
  static const int Gs[4] = {4, 3, 2, 1};
  int G = 1;
  for (int i = 0; i < 4; i++)
    if ((size_t)Gs[i] * per_h <= R_size) { G = Gs[i]; break; }
  short* tmp_g = (short*)Rp;                         // [G][4096][768]
  short* sc_g  = tmp_g + (size_t)G * NS * E;         // [g*4+n][1024][1024]

  // post-attention overlay
  size_t o2 = 0;
  float* partA = (float*)(Rp + o2); o2 += 4 * NS * E * 4;
  float* y2_f  = (float*)(Rp + o2); o2 += NS * E * 4;
  short* y2_b  = (short*)(Rp + o2); o2 += NS * E * 2;
  short* h_b   = (short*)(Rp + o2); o2 += NS * 3072 * 2;
  float* partB = (float*)cat;

  const dim3 tb(32, 8);
  // weight preprocessing
  transpose_kernel<<<dim3(24, 288, 1), tb, 0, stream>>>(Wc, WcT, 9216, 768, 0, 0);
  transpose_kernel<<<dim3(96, 24, 1),  tb, 0, stream>>>(Wfc, WfcT, 768, 3072, 0, 0);
  transpose_kernel<<<dim3(24, 96, 1),  tb, 0, stream>>>(Wp, WpT, 3072, 768, 0, 0);
  const long WN = 12L * E * E;
  cast_kernel<<<(WN / 4 + 255) / 256, 256, 0, stream>>>(Wq, Wq_c, WN);
  cast_kernel<<<(WN / 4 + 255) / 256, 256, 0, stream>>>(Wk, Wk_c, WN);
  cast_kernel<<<(WN / 4 + 255) / 256, 256, 0, stream>>>(Wv, Wv_c, WN);
  {  // Mt_h = Wk_h @ Wq_h^T : C[e'][e] = sum_f Wk[e'][f] Wq[e][f]
    GP p{};
    p.A = Wk_c; p.lda = 768; p.a_bs = (long)(E * E);
    p.B = Wq_c; p.ldb = 768; p.b_bs = (long)(E * E);
    p.C0 = Mt; p.ldc = 768; p.zmod = 1; p.cz0 = 0; p.cz1 = (long)(E * E);
    p.K = 768; p.alpha = 1.0f;
    gemm_pre<<<dim3(6, 6, 12), 256, 0, stream>>>(p);
  }
  {  // WvcT[j][h*768+e] = sum_f WcT[j][h*768+f] * Wv[e][f]
    GP p{};
    p.A = WcT; p.lda = 9216; p.a_bs = 768;
    p.B = Wv_c; p.ldb = 768; p.b_bs = (long)(E * E);
    p.C0 = WvcT; p.ldc = 9216; p.zmod = 1; p.cz0 = 0; p.cz1 = 768;
    p.K = 768; p.alpha = 1.0f;
    gemm_pre<<<dim3(6, 6, 12), 256, 0, stream>>>(p);
  }
  vw_kernel<<<2304, 256, 0, stream>>>(Wk, bq, vw);
  bcv_init<<<3, 256, 0, stream>>>(bc, bcv);
  bcv_acc<<<dim3(3, 36), 256, 0, stream>>>(Wc, bv, bcv);

  // LN + fused bvec (vw must be ready: vw_kernel launched above)
  ln_kernel<<<4096, 256, 0, stream>>>(inputs, g1, b1, vw, bvec, x_f, x_b);
  transpose_kernel<<<dim3(24, 32, 4), tb, 0, stream>>>(x_f, xT, 1024, 768,
                                                       (long)(S * E), (long)(E * S));

  const float sca = 0.03608439182435161f;  // 1/sqrt(768)
  for (int h0 = 0; h0 < 12; h0 += G) {
    {  // tmp = x @ Mt_h  (replaces q AND k projections)
      GP p{};
      p.A = x_b; p.lda = 768; p.a_bs = 0;
      p.B = Mt + (size_t)h0 * E * E; p.ldb = 768; p.b_bs = (long)(E * E);
      p.C0 = tmp_g; p.ldc = 768; p.zmod = 1; p.cz0 = 0; p.cz1 = (long)(NS * E);
      p.K = 768; p.alpha = 1.0f;
      gemm_tmp<<<dim3(32, 6, G), 256, 0, stream>>>(p);
    }
    {  // scores = (tmp x^T + b_t) / sqrt(E); row-const terms cancel in softmax
      GP p{};
      p.A = tmp_g; p.lda = 768; p.a_bs = (long)(S * E);
      p.B = x_b; p.ldb = 768; p.b_bs = (long)(S * E); p.b_zmod = 4;
      p.bias0 = bvec; p.zoff = h0;
      p.C0 = sc_g; p.ldc = 1024; p.zmod = 1; p.cz0 = 0; p.cz1 = (long)(S * S);
      p.K = 768; p.alpha = sca;
      gemm_sco<<<dim3(8, 8, 4 * G), 256, 0, stream>>>(p);
    }
    softmax_kernel<<<4 * G * 1024, 256, 0, stream>>>(sc_g);
    {  // attnx = attn @ x -> cat[h][4096][768]   (v folded into cproj)
      GP p{};
      p.A = sc_g; p.lda = 1024; p.a_bs = (long)(S * S);
      p.B = xT; p.ldb = 1024; p.b_bs = (long)(E * S); p.b_zmod = 4;
      p.C0 = cat + (size_t)h0 * NS * E; p.ldc = 768;
      p.zmod = 4; p.cz0 = (long)(S * E); p.cz1 = (long)(NS * E);
      p.K = 1024; p.alpha = 1.0f;
      gemm_pv<<<dim3(8, 6, 4 * G), 256, 0, stream>>>(p);
    }
  }

  {  // c_proj (with folded Wv): split-K=4 over head-major attnx
    GP p{};
    p.A = cat; p.lda = 768; p.a_kh = 768; p.a_hs = (long)(NS * E);
    p.B = WvcT; p.ldb = 9216;
    p.Cf = partA; p.ldc = 768; p.c_zs = (long)(NS * E); p.zmod = 1;
    p.K = 9216; p.kchunk = 2304; p.alpha = 1.0f;
    gemm_cproj<<<dim3(32, 6, 4), 256, 0, stream>>>(p);
  }
  // y = sum(partA) + (bc + bvc) + x_f; y2 = LN(y)
  reduce_ln_kernel<<<4096, 256, 0, stream>>>(partA, (long)(NS * E), 4, bcv, x_f,
                                             g2, b2, y2_f, y2_b);

  {  // fc + tanh-form gelu
    GP p{};
    p.A = y2_b; p.lda = 768;
    p.B = WfcT; p.ldb = 768;
    p.bias0 = bfc; p.C0 = h_b; p.ldc = 3072; p.zmod = 1;
    p.K = 768; p.alpha = 1.0f;
    gemm_fc<<<dim3(32, 24, 1), 256, 0, stream>>>(p);
  }
  {  // proj split-K=4
    GP p{};
    p.A = h_b; p.lda = 3072;
    p.B = WpT; p.ldb = 3072;
    p.Cf = partB; p.ldc = 768; p.c_zs = (long)(NS * E); p.zmod = 1;
    p.K = 3072; p.kchunk = 768; p.alpha = 1.0f;
    gemm_mproj<<<dim3(32, 6, 4), 256, 0, stream>>>(p);
  }
  reduce_kernel<<<3072, 256, 0, stream>>>(partB, (long)(NS * E), 4, bp, y2_f, out);
}